// Round 4
// baseline (223.578 us; speedup 1.0000x reference)
//
#include <hip/hip_runtime.h>

#define N_NODES 50000
#define N_EDGES 800000
#define D 64
#define H 128
#define NBLK 196   // ceil(N_NODES / 256)

typedef __attribute__((ext_vector_type(8))) short  short8;   // 8 bf16 (A/B frag)
typedef __attribute__((ext_vector_type(4))) float  floatx4;  // C/D frag
typedef __attribute__((ext_vector_type(4))) unsigned short ushort4v;

__device__ inline unsigned short f2bf(float f) {   // round-to-nearest-even
    unsigned u = __builtin_bit_cast(unsigned, f);
    u += 0x7FFFu + ((u >> 16) & 1u);
    return (unsigned short)(u >> 16);
}
__device__ inline float bf2f(unsigned short b) {
    unsigned u = (unsigned)b << 16;
    return __builtin_bit_cast(float, u);
}

// ---------------------------------------------------------------------------
// Prep: x (fp32) -> xb (bf16) [800000 quads], W1 -> w1t bf16 [n][k] (128x64),
// W2 -> w2t bf16 [n][k] (64x128). One kernel, thread-range split.
// ---------------------------------------------------------------------------
__global__ __launch_bounds__(256) void prep_kernel(
    const float* __restrict__ x, unsigned short* __restrict__ xb,
    const float* __restrict__ W1, unsigned short* __restrict__ w1t,
    const float* __restrict__ W2, unsigned short* __restrict__ w2t)
{
    int tid = blockIdx.x * 256 + threadIdx.x;
    if (tid < 800000) {                      // x quads
        float4 v = ((const float4*)x)[tid];
        ushort4v o;
        o.x = f2bf(v.x); o.y = f2bf(v.y); o.z = f2bf(v.z); o.w = f2bf(v.w);
        ((ushort4v*)xb)[tid] = o;
    } else {
        int i = tid - 800000;
        if (i < D * H) {                     // W1[k][n], k<64,n<128 -> w1t[n][k]
            int k = i >> 7, n = i & 127;
            w1t[n * D + k] = f2bf(W1[i]);
        } else if (i < 2 * D * H) {          // W2[k][n], k<128,n<64 -> w2t[n][k]
            int j = i - D * H;
            int k = j >> 6, n = j & 63;
            w2t[n * H + k] = f2bf(W2[j]);
        }
    }
}

// ---------------------------------------------------------------------------
// Histogram of destination nodes (800k int atomics).
// ---------------------------------------------------------------------------
__global__ __launch_bounds__(256) void hist_kernel(
    const int* __restrict__ row, int* __restrict__ counts)
{
    int e = blockIdx.x * 256 + threadIdx.x;
    if (e < N_EDGES) atomicAdd(&counts[row[e]], 1);
}

// ---------------------------------------------------------------------------
// Multi-block exclusive scan (3 kernels).
// ---------------------------------------------------------------------------
__global__ __launch_bounds__(256) void scan_a(
    const int* __restrict__ counts, int* __restrict__ bsum)
{
    int i = blockIdx.x * 256 + threadIdx.x;
    int v = (i < N_NODES) ? counts[i] : 0;
    #pragma unroll
    for (int d = 32; d; d >>= 1) v += __shfl_down(v, d);
    __shared__ int ws[4];
    int lane = threadIdx.x & 63, wid = threadIdx.x >> 6;
    if (lane == 0) ws[wid] = v;
    __syncthreads();
    if (threadIdx.x == 0) bsum[blockIdx.x] = ws[0] + ws[1] + ws[2] + ws[3];
}

__global__ __launch_bounds__(256) void scan_b(
    const int* __restrict__ bsum, int* __restrict__ bofs,
    int* __restrict__ offsets)
{
    int t = threadIdx.x, lane = t & 63, wid = t >> 6;
    int v = (t < NBLK) ? bsum[t] : 0;
    int incl = v;
    #pragma unroll
    for (int d = 1; d < 64; d <<= 1) {
        int y = __shfl_up(incl, d);
        if (lane >= d) incl += y;
    }
    __shared__ int wsum[4];
    if (lane == 63) wsum[wid] = incl;
    __syncthreads();
    int w0 = wsum[0], w1 = wsum[1], w2 = wsum[2];
    int wo = (wid == 0) ? 0 : (wid == 1) ? w0 : (wid == 2) ? w0 + w1 : w0 + w1 + w2;
    int excl = incl - v + wo;
    if (t < NBLK) bofs[t] = excl;
    if (t == NBLK - 1) offsets[N_NODES] = excl + v;
}

__global__ __launch_bounds__(256) void scan_c(
    const int* __restrict__ counts, const int* __restrict__ bofs,
    int* __restrict__ offsets, int* __restrict__ cursor)
{
    int t = threadIdx.x, lane = t & 63, wid = t >> 6;
    int i = blockIdx.x * 256 + t;
    int v = (i < N_NODES) ? counts[i] : 0;
    int incl = v;
    #pragma unroll
    for (int d = 1; d < 64; d <<= 1) {
        int y = __shfl_up(incl, d);
        if (lane >= d) incl += y;
    }
    __shared__ int wsum[4];
    if (lane == 63) wsum[wid] = incl;
    __syncthreads();
    int w0 = wsum[0], w1 = wsum[1], w2 = wsum[2];
    int wo = (wid == 0) ? 0 : (wid == 1) ? w0 : (wid == 2) ? w0 + w1 : w0 + w1 + w2;
    int excl = incl - v + wo + bofs[blockIdx.x];
    if (i < N_NODES) { offsets[i] = excl; cursor[i] = excl; }
}

// ---------------------------------------------------------------------------
// Bucket-fill CSR columns. Nontemporal store: the 16 slots of each csr line
// are claimed by edges on different XCDs, so L2 can never merge them — skip
// allocation and let HBM take the masked write (round-1 evidence: atomics
// write through at ~16 B/op vs the ~51 B/edge we measured for cached stores).
// ---------------------------------------------------------------------------
__global__ __launch_bounds__(256) void fill_kernel(
    const int* __restrict__ row, const int* __restrict__ col,
    int* __restrict__ cursor, int* __restrict__ csr_col)
{
    int e = blockIdx.x * 256 + threadIdx.x;
    if (e < N_EDGES) {
        int r = row[e];
        int pos = atomicAdd(&cursor[r], 1);
        __builtin_nontemporal_store(col[e], &csr_col[pos]);
    }
}

// ---------------------------------------------------------------------------
// Gather: h[node] = (1+eps)*x[node] + sum_nbrs xb[c]  -> hb (bf16)
// One wave per node; half-wave owns one neighbor row: lanes 0..31 read
// ushort2 (features 2fl,2fl+1) of row j, lanes 32..63 of row j+1. 8 rows in
// flight per unrolled iter; __shfl_xor(.,32) merges the two halves.
// ---------------------------------------------------------------------------
__global__ __launch_bounds__(256) void gather_kernel(
    const float* __restrict__ x, const unsigned short* __restrict__ xb,
    const int* __restrict__ offsets, const int* __restrict__ csr_col,
    const float* __restrict__ eps, unsigned short* __restrict__ hb)
{
    int t = threadIdx.x, wid = t >> 6, lane = t & 63;
    int node = blockIdx.x * 4 + wid;
    if (node >= N_NODES) return;
    int half = lane >> 5, fl = lane & 31;
    int beg = offsets[node], end = offsets[node + 1];

    float a0 = 0.f, a1 = 0.f, b0 = 0.f, b1 = 0.f;
    float c0 = 0.f, c1 = 0.f, d0 = 0.f, d1 = 0.f;
    int j = beg;
    for (; j + 8 <= end; j += 8) {
        int e0 = csr_col[j + half];
        int e1 = csr_col[j + 2 + half];
        int e2 = csr_col[j + 4 + half];
        int e3 = csr_col[j + 6 + half];
        ushort2 p0 = *(const ushort2*)&xb[e0 * D + 2 * fl];
        ushort2 p1 = *(const ushort2*)&xb[e1 * D + 2 * fl];
        ushort2 p2 = *(const ushort2*)&xb[e2 * D + 2 * fl];
        ushort2 p3 = *(const ushort2*)&xb[e3 * D + 2 * fl];
        a0 += bf2f(p0.x); a1 += bf2f(p0.y);
        b0 += bf2f(p1.x); b1 += bf2f(p1.y);
        c0 += bf2f(p2.x); c1 += bf2f(p2.y);
        d0 += bf2f(p3.x); d1 += bf2f(p3.y);
    }
    for (; j < end; j += 2) {
        if (j + half < end) {
            int e = csr_col[j + half];
            ushort2 p = *(const ushort2*)&xb[e * D + 2 * fl];
            a0 += bf2f(p.x); a1 += bf2f(p.y);
        }
    }
    float s0 = (a0 + b0) + (c0 + d0);
    float s1 = (a1 + b1) + (c1 + d1);
    s0 += __shfl_xor(s0, 32);
    s1 += __shfl_xor(s1, 32);

    if (half == 0) {
        float2 xv = *(const float2*)&x[node * D + 2 * fl];
        float ep = 1.0f + eps[0];
        ushort2 o;
        o.x = f2bf(fmaf(ep, xv.x, s0));
        o.y = f2bf(fmaf(ep, xv.y, s1));
        *(ushort2*)&hb[node * D + 2 * fl] = o;
    }
}

// ---------------------------------------------------------------------------
// MLP via bf16 MFMA 16x16x32. Block = 4 waves, wave owns 16 nodes.
// Weights arrive pre-converted/pre-transposed (w1t [128][64], w2t [64][128]);
// staging is short8 copies (8 per thread).
// ---------------------------------------------------------------------------
__global__ __launch_bounds__(256) void mlp_kernel(
    const unsigned short* __restrict__ hb,
    const unsigned short* __restrict__ w1t, const float* __restrict__ b1,
    const unsigned short* __restrict__ w2t, const float* __restrict__ b2,
    float* __restrict__ out)
{
    __shared__ unsigned short W1T[H][72];       // [n][k], pad 64->72
    __shared__ unsigned short W2T[D][136];      // [n2][k], pad 128->136
    __shared__ unsigned short HID[4][16][136];  // per-wave hidden tile

    int t = threadIdx.x;
    // 2048 short8 chunks total: 1024 for w1t (n = c>>3, kc = c&7),
    //                           1024 for w2t (n = c>>4, kc = c&15)
    for (int c = t; c < 2048; c += 256) {
        if (c < 1024) {
            int n = c >> 3, kc = c & 7;
            *(short8*)&W1T[n][kc * 8] = *(const short8*)&w1t[n * D + kc * 8];
        } else {
            int c2 = c - 1024;
            int n = c2 >> 4, kc = c2 & 15;
            *(short8*)&W2T[n][kc * 8] = *(const short8*)&w2t[n * H + kc * 8];
        }
    }
    __syncthreads();

    int lane = t & 63, wid = t >> 6;
    int m = lane & 15, q = lane >> 4;
    int tile = blockIdx.x * 64 + wid * 16;

    const unsigned short* arow = hb + (tile + m) * D + q * 8;
    short8 a0 = *(const short8*)(arow);
    short8 a1 = *(const short8*)(arow + 32);

    #pragma unroll
    for (int nt = 0; nt < 8; ++nt) {
        float bias = b1[nt * 16 + m];
        floatx4 acc = {bias, bias, bias, bias};
        short8 w0 = *(const short8*)&W1T[nt * 16 + m][q * 8];
        short8 w1 = *(const short8*)&W1T[nt * 16 + m][32 + q * 8];
        acc = __builtin_amdgcn_mfma_f32_16x16x32_bf16(a0, w0, acc, 0, 0, 0);
        acc = __builtin_amdgcn_mfma_f32_16x16x32_bf16(a1, w1, acc, 0, 0, 0);
        #pragma unroll
        for (int r = 0; r < 4; ++r) {
            float hv = fmaxf(acc[r], 0.0f);
            HID[wid][q * 4 + r][nt * 16 + m] = f2bf(hv);
        }
    }
    __syncthreads();

    short8 ha[4];
    #pragma unroll
    for (int kc = 0; kc < 4; ++kc)
        ha[kc] = *(const short8*)&HID[wid][m][kc * 32 + q * 8];

    #pragma unroll
    for (int nt2 = 0; nt2 < 4; ++nt2) {
        float bias = b2[nt2 * 16 + m];
        floatx4 acc = {bias, bias, bias, bias};
        #pragma unroll
        for (int kc = 0; kc < 4; ++kc) {
            short8 w = *(const short8*)&W2T[nt2 * 16 + m][kc * 32 + q * 8];
            acc = __builtin_amdgcn_mfma_f32_16x16x32_bf16(ha[kc], w, acc, 0, 0, 0);
        }
        #pragma unroll
        for (int r = 0; r < 4; ++r) {
            int node = tile + q * 4 + r;
            if (node < N_NODES) out[node * D + nt2 * 16 + m] = acc[r];
        }
    }
}

// ---------------------------------------------------------------------------
extern "C" void kernel_launch(void* const* d_in, const int* in_sizes, int n_in,
                              void* d_out, int out_size, void* d_ws, size_t ws_size,
                              hipStream_t stream) {
    const float* x   = (const float*)d_in[0];
    const int*   ei  = (const int*)  d_in[1];   // [2, 800000] int32
    const float* W1  = (const float*)d_in[2];
    const float* b1  = (const float*)d_in[3];
    const float* W2  = (const float*)d_in[4];
    const float* b2  = (const float*)d_in[5];
    const float* eps = (const float*)d_in[6];
    float* out = (float*)d_out;

    // ws layout (16B-aligned segments), total ~10.3 MB:
    unsigned short* hb  = (unsigned short*)d_ws;          // 3.2M bf16 (6.4 MB)
    unsigned short* w1t = hb + (size_t)N_NODES * D;       // 8192 bf16
    unsigned short* w2t = w1t + D * H;                    // 8192 bf16
    int* csr_col = (int*)(w2t + D * H);                   // 800000
    int* counts  = csr_col + N_EDGES;                     // 50000
    int* offsets = counts + N_NODES;                      // 50001
    int* cursor  = offsets + N_NODES + 1;                 // 50000
    int* bsum    = cursor + N_NODES;                      // 196
    int* bofs    = bsum + NBLK;                           // 196

    // xb (bf16 copy of x) in d_out: consumed by gather before mlp overwrites.
    unsigned short* xb = (unsigned short*)d_out;

    const int* row = ei;
    const int* col = ei + N_EDGES;

    hipMemsetAsync(counts, 0, (size_t)N_NODES * sizeof(int), stream);

    // 800000 x-quads + 16384 weight elems = 816384 threads
    prep_kernel<<<(816384 + 255) / 256, 256, 0, stream>>>(x, xb, W1, w1t, W2, w2t);
    hist_kernel<<<(N_EDGES + 255) / 256, 256, 0, stream>>>(row, counts);
    scan_a<<<NBLK, 256, 0, stream>>>(counts, bsum);
    scan_b<<<1, 256, 0, stream>>>(bsum, bofs, offsets);
    scan_c<<<NBLK, 256, 0, stream>>>(counts, bofs, offsets, cursor);
    fill_kernel<<<(N_EDGES + 255) / 256, 256, 0, stream>>>(row, col, cursor, csr_col);
    gather_kernel<<<(N_NODES + 3) / 4, 256, 0, stream>>>(x, xb, offsets, csr_col, eps, hb);
    mlp_kernel<<<(N_NODES + 63) / 64, 256, 0, stream>>>(hb, w1t, b1, w2t, b2, out);
}